// Round 5
// baseline (782.597 us; speedup 1.0000x reference)
//
#include <hip/hip_runtime.h>

// ---------------------------------------------------------------------------
// Int4 dequant-linear, two-phase:
//   1) prepass: X fp32 -> fp16 (64 MB), Q nibbles -> fp16 exact ints (86 MB) in d_ws
//   2) 256x256 8-phase fp16 MFMA GEMM (T2 swizzle + T3/T4 counted vmcnt + T5 setprio),
//      scale/bias in epilogue.
// Round-5: MFMA shape 16x16x32 -> 32x32x16 (+20% matrix-pipe FLOP/cyc, half the
// issue slots). Stage/swizzle/vmcnt-ledger byte-identical to the verified round-4.
// ---------------------------------------------------------------------------

typedef _Float16 half8 __attribute__((ext_vector_type(8)));
typedef _Float16 h2    __attribute__((ext_vector_type(2)));
typedef float    floatx4  __attribute__((ext_vector_type(4)));
typedef float    floatx16 __attribute__((ext_vector_type(16)));
typedef float    fvec4 __attribute__((ext_vector_type(4)));
typedef int      ivec4 __attribute__((ext_vector_type(4)));

constexpr int M_TOT   = 8192;
constexpr int N_TOT   = 11008;
constexpr int K_TOT   = 4096;
constexpr int PACKEDC = 2048;
constexpr int NKT     = K_TOT / 64;     // 64 K-tiles of BK=64
constexpr size_t XF_BYTES = (size_t)M_TOT * K_TOT * 2;
constexpr size_t WF_BYTES = (size_t)N_TOT * K_TOT * 2;

#define MEMFENCE() asm volatile("" ::: "memory")
static __device__ __forceinline__ void bar() {
    MEMFENCE(); __builtin_amdgcn_s_barrier(); MEMFENCE();
}

// ---------------- prepass: X fp32 -> fp16 ----------------
__global__ void cvt_x_kernel(const float* __restrict__ x, _Float16* __restrict__ xf, int n8) {
    const int stride = gridDim.x * blockDim.x;
    for (int i = blockIdx.x * blockDim.x + threadIdx.x; i < n8; i += stride) {
        const fvec4* p = (const fvec4*)(x + (size_t)i * 8);
        fvec4 a = p[0], b = p[1];
        half8 h;
        #pragma unroll
        for (int j = 0; j < 4; ++j) { h[j] = (_Float16)a[j]; h[4 + j] = (_Float16)b[j]; }
        *(half8*)(xf + (size_t)i * 8) = h;
    }
}

// ---------------- prepass: Q nibbles -> fp16 (exact ints, scale deferred) ----------------
__global__ void cvt_q_kernel(const int* __restrict__ q, _Float16* __restrict__ wf, int n4) {
    const int stride = gridDim.x * blockDim.x;
    for (int i = blockIdx.x * blockDim.x + threadIdx.x; i < n4; i += stride) {
        ivec4 d = ((const ivec4*)q)[i];
        half8 h;
        #pragma unroll
        for (int e = 0; e < 4; ++e) {
            unsigned b = (unsigned)d[e];
            unsigned u = ((b | (b << 12)) & 0x000F000Fu) | 0x64006400u;
            h2 v = __builtin_bit_cast(h2, u) - (_Float16)1032.0f;
            h[2 * e]     = v[0];
            h[2 * e + 1] = v[1];
        }
        *(half8*)(wf + (size_t)i * 8) = h;
    }
}

// ---------------- 256x256 8-phase GEMM, 32x32x16 MFMA ----------------
__global__ __launch_bounds__(512, 2)
void gemm8p_kernel(const _Float16* __restrict__ A, const _Float16* __restrict__ Bm,
                   const float* __restrict__ scale, const float* __restrict__ bias,
                   float* __restrict__ out)
{
    // [slot][mat(0=A,1=B)][half][128*64 halfs], 128 KiB total
    __shared__ _Float16 L[2][2][2][128 * 64];

    const int tid  = threadIdx.x;
    const int lane = tid & 63;
    const int wave = tid >> 6;
    const int wr   = wave >> 2;    // 0..1  (M half of tile)
    const int wc   = wave & 3;     // 0..3  (N quarter)
    const int lr   = lane & 31;    // row within 32x32 frag
    const int hi   = lane >> 5;    // k-half selector

    // XCD-bijective swizzle (1376 % 8 == 0) + band-8 M-fastest raster
    const int bid  = blockIdx.x;
    const int swz  = (bid & 7) * 172 + (bid >> 3);
    const int band = swz / 344;            // 344 = 8*43
    const int rr   = swz % 344;
    const int tm   = band * 8 + (rr & 7);  // 0..31
    const int tn   = rr >> 3;              // 0..42

    const int srow = lane >> 3;            // row within 8-row stage group
    const int sg   = lane & 7;             // LDS granule
    const int sgk  = sg ^ srow;            // pre-swizzled global granule (T2, rule #21)

    const _Float16* Ag = A  + (size_t)(tm * 256) * K_TOT;
    const _Float16* Bg = Bm + (size_t)(tn * 256) * K_TOT;

    floatx16 acc[4][2];
    #pragma unroll
    for (int i = 0; i < 4; ++i)
        #pragma unroll
        for (int j = 0; j < 2; ++j)
            acc[i][j] = (floatx16)0.0f;

    // stage one 128x64 half-tile (all 8 waves, 2 x global_load_lds each, linear dest).
    // kt CLAMPED, never skipped: keeps the per-wave vmcnt ledger identical in tail
    // iterations (round-3 bug: skipped loads broke the vmcnt(4) guarantee).
    auto stage = [&](int slot, int mat, int half, int kt) {
        if (kt >= NKT) kt = NKT - 1;   // harmless re-stage; target slot never read again
        const _Float16* gb = mat ? Bg : Ag;
        #pragma unroll
        for (int i = 0; i < 2; ++i) {
            const int row = wave * 16 + i * 8 + srow;
            const _Float16* g = gb + (size_t)(half * 128 + row) * K_TOT + kt * 64 + sgk * 8;
            _Float16* l = &L[slot][mat][half][row * 64 + sg * 8];
            __builtin_amdgcn_global_load_lds((const __attribute__((address_space(1))) void*)g,
                                             (__attribute__((address_space(3))) void*)l, 16, 0, 0);
        }
    };

    half8 a0[2][4], a1[2][4], bb[4];

    // A frag: m-pair mh covers m-frags {2mh,2mh+1}; rows (mi*32+lr), k = ks*16+hi*8
    auto ldA = [&](int slot, int mh, half8 (&d)[2][4]) {
        const char* base = (const char*)&L[slot][0][wr][0];
        #pragma unroll
        for (int m2 = 0; m2 < 2; ++m2)
            #pragma unroll
            for (int ks = 0; ks < 4; ++ks) {
                const int row = (mh * 2 + m2) * 32 + lr;
                const int off = row * 128 + ((ks * 32 + hi * 16) ^ ((row & 7) << 4));
                d[m2][ks] = *(const half8*)(base + off);
            }
    };
    auto ldB = [&](int slot, int nh) {
        const char* base = (const char*)&L[slot][1][wc >> 1][0];
        #pragma unroll
        for (int ks = 0; ks < 4; ++ks) {
            const int row = (wc & 1) * 64 + nh * 32 + lr;
            const int off = row * 128 + ((ks * 32 + hi * 16) ^ ((row & 7) << 4));
            bb[ks] = *(const half8*)(base + off);
        }
    };
    auto mma = [&](int mh, int nh, half8 (&a)[2][4]) {
        __builtin_amdgcn_s_setprio(1);
        #pragma unroll
        for (int m2 = 0; m2 < 2; ++m2)
            #pragma unroll
            for (int ks = 0; ks < 4; ++ks)
                acc[mh * 2 + m2][nh] = __builtin_amdgcn_mfma_f32_32x32x16_f16(
                    a[m2][ks], bb[ks], acc[mh * 2 + m2][nh], 0, 0, 0);
        __builtin_amdgcn_s_setprio(0);
    };

    // prologue: tile0 (A,B) + tile1 (A) = 6 half-tiles; wait for first 4 (tile0)
    stage(0, 0, 0, 0); stage(0, 0, 1, 0); stage(0, 1, 0, 0); stage(0, 1, 1, 0);
    stage(1, 0, 0, 1); stage(1, 0, 1, 1);
    asm volatile("s_waitcnt vmcnt(4)" ::: "memory");
    bar();

    #pragma unroll 1
    for (int it = 0; it < K_TOT / 128; ++it) {
        const int t1 = 2 * it + 1, t2 = 2 * it + 2, t3 = 2 * it + 3;
        // ph0: Q(0,0) of tile 2it (slot 0)
        ldA(0, 0, a0); ldB(0, 0); stage(1, 1, 0, t1);
        bar(); asm volatile("s_waitcnt lgkmcnt(0)" ::: "memory");
        mma(0, 0, a0); bar();
        // ph1: Q(1,0)
        ldA(0, 1, a1); stage(1, 1, 1, t1);
        bar(); asm volatile("s_waitcnt lgkmcnt(0)" ::: "memory");
        mma(1, 0, a1); bar();
        // ph2: Q(1,1)
        ldB(0, 1); stage(0, 0, 0, t2);
        bar(); asm volatile("s_waitcnt lgkmcnt(0)" ::: "memory");
        mma(1, 1, a1); bar();
        // ph3: Q(0,1); counted vmcnt before slot-1 reads
        stage(0, 0, 1, t2);
        bar();
        mma(0, 1, a0);
        asm volatile("s_waitcnt vmcnt(4)" ::: "memory");
        bar();
        // ph4: Q(0,0) of tile 2it+1 (slot 1)
        ldA(1, 0, a0); ldB(1, 0); stage(0, 1, 0, t2);
        bar(); asm volatile("s_waitcnt lgkmcnt(0)" ::: "memory");
        mma(0, 0, a0); bar();
        // ph5: Q(1,0)
        ldA(1, 1, a1); stage(0, 1, 1, t2);
        bar(); asm volatile("s_waitcnt lgkmcnt(0)" ::: "memory");
        mma(1, 0, a1); bar();
        // ph6: Q(1,1)
        ldB(1, 1); stage(1, 0, 0, t3);
        bar(); asm volatile("s_waitcnt lgkmcnt(0)" ::: "memory");
        mma(1, 1, a1); bar();
        // ph7: Q(0,1); counted vmcnt before next-iter slot-0 reads
        stage(1, 0, 1, t3);
        bar();
        mma(0, 1, a0);
        asm volatile("s_waitcnt vmcnt(4)" ::: "memory");
        bar();
    }

    // drain remaining async LDS-writes before epilogue / wave exit
    asm volatile("s_waitcnt vmcnt(0)" ::: "memory");

    // epilogue: out = acc * scale[col] + bias[col]
    // 32x32 C/D layout: col = lane&31, row = (reg&3) + 8*(reg>>2) + 4*(lane>>5)
    #pragma unroll
    for (int ni = 0; ni < 2; ++ni) {
        const int col = tn * 256 + wc * 64 + ni * 32 + lr;
        const float s  = scale[col];
        const float bv = bias[col];
        #pragma unroll
        for (int mi = 0; mi < 4; ++mi) {
            const int row0 = tm * 256 + wr * 128 + mi * 32 + hi * 4;
            #pragma unroll
            for (int q = 0; q < 4; ++q)
                #pragma unroll
                for (int j = 0; j < 4; ++j)
                    out[(size_t)(row0 + q * 8 + j) * N_TOT + col] = acc[mi][ni][q * 4 + j] * s + bv;
        }
    }
}

// ---------------- fallback: round-1 fused kernel (known good) ----------------
constexpr int LDSS = 40;

__global__ __launch_bounds__(256, 2)
void int4lin_fused_kernel(const float* __restrict__ X,
                          const int*   __restrict__ Q,
                          const float* __restrict__ scale,
                          const float* __restrict__ bias,
                          float*       __restrict__ out)
{
    __shared__ _Float16 As[2][128][LDSS];
    __shared__ _Float16 Bs[2][128][LDSS];

    const int tid  = threadIdx.x;
    const int lane = tid & 63;
    const int bx   = blockIdx.x;
    const int by   = blockIdx.y;
    const int wave = tid >> 6;
    const int wm   = (wave >> 1) * 64;
    const int wn   = (wave & 1) * 64;
    const int fr   = lane & 15;
    const int kg   = lane >> 4;

    const int srow  = tid >> 1;
    const int shalf = tid & 1;

    const float* aptr = X + (size_t)(by * 128 + srow) * K_TOT + shalf * 16;
    const int*   bptr = Q + (size_t)(bx * 128 + srow) * PACKEDC + shalf * 8;

    floatx4 acc[4][4];
    #pragma unroll
    for (int i = 0; i < 4; ++i)
        #pragma unroll
        for (int j = 0; j < 4; ++j)
            acc[i][j] = (floatx4)0.0f;

    fvec4 araw[4];
    ivec4 braw[2];

    auto gload = [&](int kt) {
        const fvec4* ap = (const fvec4*)(aptr + (size_t)kt * 32);
        #pragma unroll
        for (int i = 0; i < 4; ++i) araw[i] = ap[i];
        const ivec4* bp = (const ivec4*)(bptr + kt * 16);
        #pragma unroll
        for (int i = 0; i < 2; ++i) braw[i] = bp[i];
    };

    auto cvt_write = [&](int buf) {
        #pragma unroll
        for (int v = 0; v < 2; ++v) {
            half8 h;
            #pragma unroll
            for (int e = 0; e < 8; ++e)
                h[e] = (_Float16)araw[v * 2 + (e >> 2)][e & 3];
            *(half8*)&As[buf][srow][shalf * 16 + v * 8] = h;
        }
        #pragma unroll
        for (int v = 0; v < 2; ++v) {
            half8 h;
            #pragma unroll
            for (int e = 0; e < 4; ++e) {
                const int b = braw[v][e];
                h[2 * e]     = (_Float16)((b & 15) - 8);
                h[2 * e + 1] = (_Float16)((b >> 4) - 8);
            }
            *(half8*)&Bs[buf][srow][shalf * 16 + v * 8] = h;
        }
    };

    gload(0);
    cvt_write(0);
    __syncthreads();

    int cur = 0;
    #pragma unroll 1
    for (int kt = 0; kt < K_TOT / 32; ++kt) {
        if (kt + 1 < K_TOT / 32) gload(kt + 1);

        half8 af[4], bf[4];
        #pragma unroll
        for (int mi = 0; mi < 4; ++mi)
            af[mi] = *(const half8*)&As[cur][wm + mi * 16 + fr][kg * 8];
        #pragma unroll
        for (int ni = 0; ni < 4; ++ni)
            bf[ni] = *(const half8*)&Bs[cur][wn + ni * 16 + fr][kg * 8];

        #pragma unroll
        for (int mi = 0; mi < 4; ++mi)
            #pragma unroll
            for (int ni = 0; ni < 4; ++ni)
                acc[mi][ni] = __builtin_amdgcn_mfma_f32_16x16x32_f16(
                    af[mi], bf[ni], acc[mi][ni], 0, 0, 0);

        if (kt + 1 < K_TOT / 32) cvt_write(cur ^ 1);
        __syncthreads();
        cur ^= 1;
    }

    #pragma unroll
    for (int ni = 0; ni < 4; ++ni) {
        const int col = bx * 128 + wn + ni * 16 + fr;
        const float s  = scale[col];
        const float bv = bias[col];
        #pragma unroll
        for (int mi = 0; mi < 4; ++mi) {
            const int row0 = by * 128 + wm + mi * 16 + kg * 4;
            #pragma unroll
            for (int j = 0; j < 4; ++j)
                out[(size_t)(row0 + j) * N_TOT + col] = acc[mi][ni][j] * s + bv;
        }
    }
}

extern "C" void kernel_launch(void* const* d_in, const int* in_sizes, int n_in,
                              void* d_out, int out_size, void* d_ws, size_t ws_size,
                              hipStream_t stream) {
    const float* x     = (const float*)d_in[0];
    const int*   q     = (const int*)d_in[1];
    const float* scale = (const float*)d_in[2];
    const float* bias  = (const float*)d_in[3];
    float*       out   = (float*)d_out;

    if (ws_size >= XF_BYTES + WF_BYTES) {
        _Float16* xf = (_Float16*)d_ws;
        _Float16* wf = (_Float16*)((char*)d_ws + XF_BYTES);
        cvt_x_kernel<<<2048, 256, 0, stream>>>(x, xf, M_TOT * K_TOT / 8);
        cvt_q_kernel<<<2048, 256, 0, stream>>>(q, wf, N_TOT * PACKEDC / 4);
        gemm8p_kernel<<<(M_TOT / 256) * (N_TOT / 256), 512, 0, stream>>>(xf, wf, scale, bias, out);
    } else {
        dim3 grid(N_TOT / 128, M_TOT / 128);
        int4lin_fused_kernel<<<grid, dim3(256), 0, stream>>>(x, q, scale, bias, out);
    }
}

// Round 6
// 681.766 us; speedup vs baseline: 1.1479x; 1.1479x over previous
//
#include <hip/hip_runtime.h>

// ---------------------------------------------------------------------------
// Int4 dequant-linear, two-phase:
//   1) prepass: X fp32 -> fp16 (64 MB), Q nibbles -> fp16 exact ints (86 MB) in d_ws
//   2) 256x256 8-phase fp16 MFMA GEMM (T2 swizzle + T3/T4 counted vmcnt + T5 setprio),
//      scale/bias in epilogue. 16x16x32 MFMA (round-5's 32x32 regressed: 4-way LDS
//      read conflicts, 128B rows can only spread 8 rows via XOR).
// Round-6: revert to round-4 core + nontemporal epilogue stores / prepass loads
// (output stream was evicting L3-resident input panels -> 630 MB FETCH) +
// lgkmcnt(8) pre-drain hint in 12-ds_read phases.
// ---------------------------------------------------------------------------

typedef _Float16 half8 __attribute__((ext_vector_type(8)));
typedef _Float16 h2    __attribute__((ext_vector_type(2)));
typedef float    floatx4 __attribute__((ext_vector_type(4)));
typedef float    fvec4 __attribute__((ext_vector_type(4)));
typedef int      ivec4 __attribute__((ext_vector_type(4)));

constexpr int M_TOT   = 8192;
constexpr int N_TOT   = 11008;
constexpr int K_TOT   = 4096;
constexpr int PACKEDC = 2048;
constexpr int NKT     = K_TOT / 64;     // 64 K-tiles of BK=64
constexpr size_t XF_BYTES = (size_t)M_TOT * K_TOT * 2;
constexpr size_t WF_BYTES = (size_t)N_TOT * K_TOT * 2;

#define MEMFENCE() asm volatile("" ::: "memory")
static __device__ __forceinline__ void bar() {
    MEMFENCE(); __builtin_amdgcn_s_barrier(); MEMFENCE();
}

// ---------------- prepass: X fp32 -> fp16 ----------------
__global__ void cvt_x_kernel(const float* __restrict__ x, _Float16* __restrict__ xf, int n8) {
    const int stride = gridDim.x * blockDim.x;
    for (int i = blockIdx.x * blockDim.x + threadIdx.x; i < n8; i += stride) {
        const fvec4* p = (const fvec4*)(x + (size_t)i * 8);
        fvec4 a = __builtin_nontemporal_load(p);
        fvec4 b = __builtin_nontemporal_load(p + 1);
        half8 h;
        #pragma unroll
        for (int j = 0; j < 4; ++j) { h[j] = (_Float16)a[j]; h[4 + j] = (_Float16)b[j]; }
        *(half8*)(xf + (size_t)i * 8) = h;   // re-read by GEMM: keep cached
    }
}

// ---------------- prepass: Q nibbles -> fp16 (exact ints, scale deferred) ----------------
__global__ void cvt_q_kernel(const int* __restrict__ q, _Float16* __restrict__ wf, int n4) {
    const int stride = gridDim.x * blockDim.x;
    for (int i = blockIdx.x * blockDim.x + threadIdx.x; i < n4; i += stride) {
        ivec4 d = __builtin_nontemporal_load((const ivec4*)q + i);
        half8 h;
        #pragma unroll
        for (int e = 0; e < 4; ++e) {
            unsigned b = (unsigned)d[e];
            unsigned u = ((b | (b << 12)) & 0x000F000Fu) | 0x64006400u;
            h2 v = __builtin_bit_cast(h2, u) - (_Float16)1032.0f;
            h[2 * e]     = v[0];
            h[2 * e + 1] = v[1];
        }
        *(half8*)(wf + (size_t)i * 8) = h;   // re-read by GEMM: keep cached
    }
}

// ---------------- 256x256 8-phase GEMM, 16x16x32 MFMA ----------------
__global__ __launch_bounds__(512, 2)
void gemm8p_kernel(const _Float16* __restrict__ A, const _Float16* __restrict__ Bm,
                   const float* __restrict__ scale, const float* __restrict__ bias,
                   float* __restrict__ out)
{
    // [slot][mat(0=A,1=B)][half][128*64 halfs], 128 KiB total
    __shared__ _Float16 L[2][2][2][128 * 64];

    const int tid  = threadIdx.x;
    const int lane = tid & 63;
    const int wave = tid >> 6;
    const int wr   = wave >> 2;    // 0..1  (M half of tile)
    const int wc   = wave & 3;     // 0..3  (N quarter)
    const int fr   = lane & 15;
    const int kg   = lane >> 4;

    // XCD-bijective swizzle (1376 % 8 == 0) + band-8 M-fastest raster
    const int bid  = blockIdx.x;
    const int swz  = (bid & 7) * 172 + (bid >> 3);
    const int band = swz / 344;            // 344 = 8*43
    const int rr   = swz % 344;
    const int tm   = band * 8 + (rr & 7);  // 0..31
    const int tn   = rr >> 3;              // 0..42

    const int srow = lane >> 3;            // row within 8-row stage group
    const int sg   = lane & 7;             // LDS granule
    const int sgk  = sg ^ srow;            // pre-swizzled global granule (T2, rule #21)

    const _Float16* Ag = A  + (size_t)(tm * 256) * K_TOT;
    const _Float16* Bg = Bm + (size_t)(tn * 256) * K_TOT;

    floatx4 acc[8][4];
    #pragma unroll
    for (int i = 0; i < 8; ++i)
        #pragma unroll
        for (int j = 0; j < 4; ++j)
            acc[i][j] = (floatx4)0.0f;

    // stage one 128x64 half-tile (all 8 waves, 2 x global_load_lds each, linear dest).
    // kt CLAMPED, never skipped: keeps the per-wave vmcnt ledger identical in tail
    // iterations (round-3 bug: skipped loads broke the vmcnt(4) guarantee).
    auto stage = [&](int slot, int mat, int half, int kt) {
        if (kt >= NKT) kt = NKT - 1;   // harmless re-stage; target slot never read again
        const _Float16* gb = mat ? Bg : Ag;
        #pragma unroll
        for (int i = 0; i < 2; ++i) {
            const int row = wave * 16 + i * 8 + srow;
            const _Float16* g = gb + (size_t)(half * 128 + row) * K_TOT + kt * 64 + sgk * 8;
            _Float16* l = &L[slot][mat][half][row * 64 + sg * 8];
            __builtin_amdgcn_global_load_lds((const __attribute__((address_space(1))) void*)g,
                                             (__attribute__((address_space(3))) void*)l, 16, 0, 0);
        }
    };

    half8 a0[4][2], a1[4][2], bb[2][2];

    auto ldA = [&](int slot, int mh, half8 (&d)[4][2]) {
        const char* base = (const char*)&L[slot][0][wr][0];
        #pragma unroll
        for (int m4 = 0; m4 < 4; ++m4)
            #pragma unroll
            for (int ks = 0; ks < 2; ++ks) {
                const int row = (mh * 4 + m4) * 16 + fr;
                const int off = row * 128 + ((ks * 64 + kg * 16) ^ ((fr & 7) << 4));
                d[m4][ks] = *(const half8*)(base + off);
            }
    };
    auto ldB = [&](int slot, int nh) {
        const char* base = (const char*)&L[slot][1][wc >> 1][0];
        #pragma unroll
        for (int n2 = 0; n2 < 2; ++n2)
            #pragma unroll
            for (int ks = 0; ks < 2; ++ks) {
                const int row = (wc & 1) * 64 + (nh * 2 + n2) * 16 + fr;
                const int off = row * 128 + ((ks * 64 + kg * 16) ^ ((fr & 7) << 4));
                bb[n2][ks] = *(const half8*)(base + off);
            }
    };
    auto mma = [&](int mh, int nh, half8 (&a)[4][2]) {
        __builtin_amdgcn_s_setprio(1);
        #pragma unroll
        for (int m4 = 0; m4 < 4; ++m4)
            #pragma unroll
            for (int n2 = 0; n2 < 2; ++n2)
                #pragma unroll
                for (int ks = 0; ks < 2; ++ks)
                    acc[mh * 4 + m4][nh * 2 + n2] = __builtin_amdgcn_mfma_f32_16x16x32_f16(
                        a[m4][ks], bb[n2][ks], acc[mh * 4 + m4][nh * 2 + n2], 0, 0, 0);
        __builtin_amdgcn_s_setprio(0);
    };

    // prologue: tile0 (A,B) + tile1 (A) = 6 half-tiles; wait for first 4 (tile0)
    stage(0, 0, 0, 0); stage(0, 0, 1, 0); stage(0, 1, 0, 0); stage(0, 1, 1, 0);
    stage(1, 0, 0, 1); stage(1, 0, 1, 1);
    asm volatile("s_waitcnt vmcnt(4)" ::: "memory");
    bar();

    #pragma unroll 1
    for (int it = 0; it < K_TOT / 128; ++it) {
        const int t1 = 2 * it + 1, t2 = 2 * it + 2, t3 = 2 * it + 3;
        // ph0: Q(0,0) of tile 2it (slot 0); 12 ds_reads -> pre-drain to 8
        ldA(0, 0, a0); ldB(0, 0); stage(1, 1, 0, t1);
        asm volatile("s_waitcnt lgkmcnt(8)" ::: "memory");
        bar(); asm volatile("s_waitcnt lgkmcnt(0)" ::: "memory");
        mma(0, 0, a0); bar();
        // ph1: Q(1,0)
        ldA(0, 1, a1); stage(1, 1, 1, t1);
        bar(); asm volatile("s_waitcnt lgkmcnt(0)" ::: "memory");
        mma(1, 0, a1); bar();
        // ph2: Q(1,1)
        ldB(0, 1); stage(0, 0, 0, t2);
        bar(); asm volatile("s_waitcnt lgkmcnt(0)" ::: "memory");
        mma(1, 1, a1); bar();
        // ph3: Q(0,1); counted vmcnt before slot-1 reads
        stage(0, 0, 1, t2);
        bar();
        mma(0, 1, a0);
        asm volatile("s_waitcnt vmcnt(4)" ::: "memory");
        bar();
        // ph4: Q(0,0) of tile 2it+1 (slot 1); 12 ds_reads -> pre-drain to 8
        ldA(1, 0, a0); ldB(1, 0); stage(0, 1, 0, t2);
        asm volatile("s_waitcnt lgkmcnt(8)" ::: "memory");
        bar(); asm volatile("s_waitcnt lgkmcnt(0)" ::: "memory");
        mma(0, 0, a0); bar();
        // ph5: Q(1,0)
        ldA(1, 1, a1); stage(0, 1, 1, t2);
        bar(); asm volatile("s_waitcnt lgkmcnt(0)" ::: "memory");
        mma(1, 0, a1); bar();
        // ph6: Q(1,1)
        ldB(1, 1); stage(1, 0, 0, t3);
        bar(); asm volatile("s_waitcnt lgkmcnt(0)" ::: "memory");
        mma(1, 1, a1); bar();
        // ph7: Q(0,1); counted vmcnt before next-iter slot-0 reads
        stage(1, 0, 1, t3);
        bar();
        mma(0, 1, a0);
        asm volatile("s_waitcnt vmcnt(4)" ::: "memory");
        bar();
    }

    // drain remaining async LDS-writes before epilogue / wave exit
    asm volatile("s_waitcnt vmcnt(0)" ::: "memory");

    // epilogue: out = acc * scale[col] + bias[col]; nontemporal (never re-read,
    // and the 360 MB output stream was evicting the L3-resident input panels)
    #pragma unroll
    for (int ni = 0; ni < 4; ++ni) {
        const int col = tn * 256 + wc * 64 + ni * 16 + fr;
        const float s  = scale[col];
        const float bv = bias[col];
        #pragma unroll
        for (int mi = 0; mi < 8; ++mi) {
            const int row0 = tm * 256 + wr * 128 + mi * 16 + kg * 4;
            #pragma unroll
            for (int j = 0; j < 4; ++j)
                __builtin_nontemporal_store(acc[mi][ni][j] * s + bv,
                                            out + (size_t)(row0 + j) * N_TOT + col);
        }
    }
}

// ---------------- fallback: round-1 fused kernel (known good) ----------------
constexpr int LDSS = 40;

__global__ __launch_bounds__(256, 2)
void int4lin_fused_kernel(const float* __restrict__ X,
                          const int*   __restrict__ Q,
                          const float* __restrict__ scale,
                          const float* __restrict__ bias,
                          float*       __restrict__ out)
{
    __shared__ _Float16 As[2][128][LDSS];
    __shared__ _Float16 Bs[2][128][LDSS];

    const int tid  = threadIdx.x;
    const int lane = tid & 63;
    const int bx   = blockIdx.x;
    const int by   = blockIdx.y;
    const int wave = tid >> 6;
    const int wm   = (wave >> 1) * 64;
    const int wn   = (wave & 1) * 64;
    const int fr   = lane & 15;
    const int kg   = lane >> 4;

    const int srow  = tid >> 1;
    const int shalf = tid & 1;

    const float* aptr = X + (size_t)(by * 128 + srow) * K_TOT + shalf * 16;
    const int*   bptr = Q + (size_t)(bx * 128 + srow) * PACKEDC + shalf * 8;

    floatx4 acc[4][4];
    #pragma unroll
    for (int i = 0; i < 4; ++i)
        #pragma unroll
        for (int j = 0; j < 4; ++j)
            acc[i][j] = (floatx4)0.0f;

    fvec4 araw[4];
    ivec4 braw[2];

    auto gload = [&](int kt) {
        const fvec4* ap = (const fvec4*)(aptr + (size_t)kt * 32);
        #pragma unroll
        for (int i = 0; i < 4; ++i) araw[i] = ap[i];
        const ivec4* bp = (const ivec4*)(bptr + kt * 16);
        #pragma unroll
        for (int i = 0; i < 2; ++i) braw[i] = bp[i];
    };

    auto cvt_write = [&](int buf) {
        #pragma unroll
        for (int v = 0; v < 2; ++v) {
            half8 h;
            #pragma unroll
            for (int e = 0; e < 8; ++e)
                h[e] = (_Float16)araw[v * 2 + (e >> 2)][e & 3];
            *(half8*)&As[buf][srow][shalf * 16 + v * 8] = h;
        }
        #pragma unroll
        for (int v = 0; v < 2; ++v) {
            half8 h;
            #pragma unroll
            for (int e = 0; e < 4; ++e) {
                const int b = braw[v][e];
                h[2 * e]     = (_Float16)((b & 15) - 8);
                h[2 * e + 1] = (_Float16)((b >> 4) - 8);
            }
            *(half8*)&Bs[buf][srow][shalf * 16 + v * 8] = h;
        }
    };

    gload(0);
    cvt_write(0);
    __syncthreads();

    int cur = 0;
    #pragma unroll 1
    for (int kt = 0; kt < K_TOT / 32; ++kt) {
        if (kt + 1 < K_TOT / 32) gload(kt + 1);

        half8 af[4], bf[4];
        #pragma unroll
        for (int mi = 0; mi < 4; ++mi)
            af[mi] = *(const half8*)&As[cur][wm + mi * 16 + fr][kg * 8];
        #pragma unroll
        for (int ni = 0; ni < 4; ++ni)
            bf[ni] = *(const half8*)&Bs[cur][wn + ni * 16 + fr][kg * 8];

        #pragma unroll
        for (int mi = 0; mi < 4; ++mi)
            #pragma unroll
            for (int ni = 0; ni < 4; ++ni)
                acc[mi][ni] = __builtin_amdgcn_mfma_f32_16x16x32_f16(
                    af[mi], bf[ni], acc[mi][ni], 0, 0, 0);

        if (kt + 1 < K_TOT / 32) cvt_write(cur ^ 1);
        __syncthreads();
        cur ^= 1;
    }

    #pragma unroll
    for (int ni = 0; ni < 4; ++ni) {
        const int col = bx * 128 + wn + ni * 16 + fr;
        const float s  = scale[col];
        const float bv = bias[col];
        #pragma unroll
        for (int mi = 0; mi < 4; ++mi) {
            const int row0 = by * 128 + wm + mi * 16 + kg * 4;
            #pragma unroll
            for (int j = 0; j < 4; ++j)
                out[(size_t)(row0 + j) * N_TOT + col] = acc[mi][ni][j] * s + bv;
        }
    }
}

extern "C" void kernel_launch(void* const* d_in, const int* in_sizes, int n_in,
                              void* d_out, int out_size, void* d_ws, size_t ws_size,
                              hipStream_t stream) {
    const float* x     = (const float*)d_in[0];
    const int*   q     = (const int*)d_in[1];
    const float* scale = (const float*)d_in[2];
    const float* bias  = (const float*)d_in[3];
    float*       out   = (float*)d_out;

    if (ws_size >= XF_BYTES + WF_BYTES) {
        _Float16* xf = (_Float16*)d_ws;
        _Float16* wf = (_Float16*)((char*)d_ws + XF_BYTES);
        cvt_x_kernel<<<2048, 256, 0, stream>>>(x, xf, M_TOT * K_TOT / 8);
        cvt_q_kernel<<<2048, 256, 0, stream>>>(q, wf, N_TOT * PACKEDC / 4);
        gemm8p_kernel<<<(M_TOT / 256) * (N_TOT / 256), 512, 0, stream>>>(xf, wf, scale, bias, out);
    } else {
        dim3 grid(N_TOT / 128, M_TOT / 128);
        int4lin_fused_kernel<<<grid, dim3(256), 0, stream>>>(x, q, scale, bias, out);
    }
}

// Round 8
// 426.244 us; speedup vs baseline: 1.8360x; 1.5995x over previous
//
#include <hip/hip_runtime.h>

// ---------------------------------------------------------------------------
// Int4 dequant-linear, int8 path:
//   1) prepass: X fp32 -> int8 per-row symmetric quant (32 MB + 8192 scales),
//      Q nibbles -> int8 exact (43 MB), both in d_ws
//   2) 256x256 8-phase i8 MFMA GEMM (mfma_i32_16x16x64_i8, BK=128): byte-identical
//      LDS geometry / swizzle / vmcnt ledger to the verified round-4 fp16 kernel,
//      but each phase covers 2x the K -> half the phases -> half the schedule
//      overhead per FLOP. Dequant (s_row * scale_col) + bias in epilogue, exact
//      int32 accumulation.
// Round-8 fix: qweight stores ONE packed byte per int32 element (round-7 treated
// it as a dense byte stream -> garbage weights). quant_q now consumes 8 int32 ->
// 16 int8, matching the round-1/2 proven indexing.
// ---------------------------------------------------------------------------

typedef _Float16 half8 __attribute__((ext_vector_type(8)));
typedef float    floatx4 __attribute__((ext_vector_type(4)));
typedef float    fvec4 __attribute__((ext_vector_type(4)));
typedef int      ivec4 __attribute__((ext_vector_type(4)));

constexpr int M_TOT   = 8192;
constexpr int N_TOT   = 11008;
constexpr int K_TOT   = 4096;
constexpr int PACKEDC = 2048;
constexpr int NKT     = K_TOT / 128;    // 32 K-tiles of BK=128 (int8)
constexpr size_t XQ_BYTES = (size_t)M_TOT * K_TOT;       // 32 MiB int8
constexpr size_t SM_BYTES = (size_t)M_TOT * 4;           // per-row scales
constexpr size_t WQ_BYTES = (size_t)N_TOT * K_TOT;       // 43 MiB int8

#define MEMFENCE() asm volatile("" ::: "memory")
static __device__ __forceinline__ void bar() {
    MEMFENCE(); __builtin_amdgcn_s_barrier(); MEMFENCE();
}

// ---------------- prepass: X fp32 -> int8, per-row symmetric ----------------
__global__ __launch_bounds__(256)
void quant_x_kernel(const float* __restrict__ x, signed char* __restrict__ xq,
                    float* __restrict__ sm)
{
    const int row = blockIdx.x;
    const int t   = threadIdx.x;
    const float* xr = x + (size_t)row * K_TOT;

    fvec4 v[4];
    #pragma unroll
    for (int k = 0; k < 4; ++k) v[k] = ((const fvec4*)xr)[t + 256 * k];

    float mx = 0.0f;
    #pragma unroll
    for (int k = 0; k < 4; ++k)
        #pragma unroll
        for (int j = 0; j < 4; ++j) mx = fmaxf(mx, __builtin_fabsf(v[k][j]));

    #pragma unroll
    for (int off = 32; off >= 1; off >>= 1) mx = fmaxf(mx, __shfl_xor(mx, off, 64));
    __shared__ float wm[4];
    if ((t & 63) == 0) wm[t >> 6] = mx;
    __syncthreads();
    mx = fmaxf(fmaxf(wm[0], wm[1]), fmaxf(wm[2], wm[3]));
    mx = fmaxf(mx, 1e-20f);
    const float inv = 127.0f / mx;
    if (t == 0) sm[row] = mx / 127.0f;

    signed char* oq = xq + (size_t)row * K_TOT;
    #pragma unroll
    for (int k = 0; k < 4; ++k) {
        unsigned w = 0;
        #pragma unroll
        for (int j = 0; j < 4; ++j) {
            int q = (int)rintf(v[k][j] * inv);
            q = q > 127 ? 127 : (q < -127 ? -127 : q);
            w |= (unsigned)(q & 0xFF) << (8 * j);
        }
        *(unsigned*)(oq + t * 4 + 1024 * k) = w;   // elems 4t+1024k .. +3
    }
}

// ---------------- prepass: Q nibbles -> int8 (exact, scale deferred) ----------------
// qweight: ONE packed byte per int32 element (value 0..255). Per element b:
// lo = (b&15)-8 at k=2p, hi = (b>>4)-8 at k=2p+1. 8 int32 -> 16 int8 per thread.
__global__ void quant_q_kernel(const int* __restrict__ q, signed char* __restrict__ wq, int n8) {
    const int stride = gridDim.x * blockDim.x;
    for (int i = blockIdx.x * blockDim.x + threadIdx.x; i < n8; i += stride) {
        int ow[4];
        #pragma unroll
        for (int h = 0; h < 2; ++h) {
            ivec4 d = ((const ivec4*)q)[2 * i + h];      // 4 packed bytes
            #pragma unroll
            for (int e = 0; e < 2; ++e) {
                const int b0 = d[2 * e], b1 = d[2 * e + 1];
                ow[2 * h + e] = (int)( (unsigned)(((b0 & 15) - 8) & 0xFF)
                                     | ((unsigned)((((b0 >> 4) & 15) - 8) & 0xFF) << 8)
                                     | ((unsigned)(((b1 & 15) - 8) & 0xFF) << 16)
                                     | ((unsigned)((((b1 >> 4) & 15) - 8) & 0xFF) << 24));
            }
        }
        *(ivec4*)(wq + (size_t)i * 16) = *(ivec4*)ow;    // k = 16*i .. 16*i+15
    }
}

// ---------------- 256x256 8-phase GEMM, i8 MFMA, BK=128 ----------------
__global__ __launch_bounds__(512, 2)
void gemm8p_i8_kernel(const signed char* __restrict__ A, const signed char* __restrict__ Bm,
                      const float* __restrict__ sm, const float* __restrict__ scale,
                      const float* __restrict__ bias, float* __restrict__ out)
{
    // [slot][mat(0=A,1=B)][half][128 rows * 128 bytes], 128 KiB total
    // (byte-identical geometry to the round-4 fp16 kernel: BK=128 int8 == BK=64 fp16)
    __shared__ signed char L[2][2][2][128 * 128];

    const int tid  = threadIdx.x;
    const int lane = tid & 63;
    const int wave = tid >> 6;
    const int wr   = wave >> 2;    // 0..1  (M half of tile)
    const int wc   = wave & 3;     // 0..3  (N quarter)
    const int fr   = lane & 15;
    const int kg   = lane >> 4;

    // XCD-bijective swizzle (1376 % 8 == 0) + band-8 M-fastest raster
    const int bid  = blockIdx.x;
    const int swz  = (bid & 7) * 172 + (bid >> 3);
    const int band = swz / 344;            // 344 = 8*43
    const int rr   = swz % 344;
    const int tm   = band * 8 + (rr & 7);  // 0..31
    const int tn   = rr >> 3;              // 0..42

    const int srow = lane >> 3;            // row within 8-row stage group
    const int sg   = lane & 7;             // LDS granule (16B)
    const int sgk  = sg ^ srow;            // pre-swizzled global granule (T2, rule #21)

    const signed char* Ag = A  + (size_t)(tm * 256) * K_TOT;
    const signed char* Bg = Bm + (size_t)(tn * 256) * K_TOT;

    ivec4 acc[8][4];
    #pragma unroll
    for (int i = 0; i < 8; ++i)
        #pragma unroll
        for (int j = 0; j < 4; ++j)
            acc[i][j] = (ivec4)0;

    // stage one 128-row x 128-byte half-tile (2 x global_load_lds/thread, linear dest).
    // kt CLAMPED, never skipped: preserves the vmcnt ledger in tail iterations.
    auto stage = [&](int slot, int mat, int half, int kt) {
        if (kt >= NKT) kt = NKT - 1;   // harmless re-stage; target slot never read again
        const signed char* gb = mat ? Bg : Ag;
        #pragma unroll
        for (int i = 0; i < 2; ++i) {
            const int row = wave * 16 + i * 8 + srow;
            const signed char* g = gb + (size_t)(half * 128 + row) * K_TOT + kt * 128 + sgk * 16;
            signed char* l = &L[slot][mat][half][row * 128 + sg * 16];
            __builtin_amdgcn_global_load_lds((const __attribute__((address_space(1))) void*)g,
                                             (__attribute__((address_space(3))) void*)l, 16, 0, 0);
        }
    };

    ivec4 a0[4][2], a1[4][2], bb[2][2];

    // frag: 16 int8 (k-span 16) per lane; kg*16B granule, ks*64B = K=64 halves of BK=128.
    // A and B use the IDENTICAL (lane,reg)->(row,k) pattern, so any HW K-permutation
    // applies symmetrically and cancels in the dot product.
    auto ldA = [&](int slot, int mh, ivec4 (&d)[4][2]) {
        const char* base = (const char*)&L[slot][0][wr][0];
        #pragma unroll
        for (int m4 = 0; m4 < 4; ++m4)
            #pragma unroll
            for (int ks = 0; ks < 2; ++ks) {
                const int row = (mh * 4 + m4) * 16 + fr;
                const int off = row * 128 + ((ks * 64 + kg * 16) ^ ((fr & 7) << 4));
                d[m4][ks] = *(const ivec4*)(base + off);
            }
    };
    auto ldB = [&](int slot, int nh) {
        const char* base = (const char*)&L[slot][1][wc >> 1][0];
        #pragma unroll
        for (int n2 = 0; n2 < 2; ++n2)
            #pragma unroll
            for (int ks = 0; ks < 2; ++ks) {
                const int row = (wc & 1) * 64 + (nh * 2 + n2) * 16 + fr;
                const int off = row * 128 + ((ks * 64 + kg * 16) ^ ((fr & 7) << 4));
                bb[n2][ks] = *(const ivec4*)(base + off);
            }
    };
    auto mma = [&](int mh, int nh, ivec4 (&a)[4][2]) {
        __builtin_amdgcn_s_setprio(1);
        #pragma unroll
        for (int m4 = 0; m4 < 4; ++m4)
            #pragma unroll
            for (int n2 = 0; n2 < 2; ++n2)
                #pragma unroll
                for (int ks = 0; ks < 2; ++ks)
                    acc[mh * 4 + m4][nh * 2 + n2] = __builtin_amdgcn_mfma_i32_16x16x64_i8(
                        a[m4][ks], bb[n2][ks], acc[mh * 4 + m4][nh * 2 + n2], 0, 0, 0);
        __builtin_amdgcn_s_setprio(0);
    };

    // prologue: tile0 (A,B) + tile1 (A) = 6 half-tiles; wait for first 4 (tile0)
    stage(0, 0, 0, 0); stage(0, 0, 1, 0); stage(0, 1, 0, 0); stage(0, 1, 1, 0);
    stage(1, 0, 0, 1); stage(1, 0, 1, 1);
    asm volatile("s_waitcnt vmcnt(4)" ::: "memory");
    bar();

    #pragma unroll 1
    for (int it = 0; it < K_TOT / 256; ++it) {
        const int t1 = 2 * it + 1, t2 = 2 * it + 2, t3 = 2 * it + 3;
        // ph0: Q(0,0) of tile 2it (slot 0); 12 ds_reads -> pre-drain to 8
        ldA(0, 0, a0); ldB(0, 0); stage(1, 1, 0, t1);
        asm volatile("s_waitcnt lgkmcnt(8)" ::: "memory");
        bar(); asm volatile("s_waitcnt lgkmcnt(0)" ::: "memory");
        mma(0, 0, a0); bar();
        // ph1: Q(1,0)
        ldA(0, 1, a1); stage(1, 1, 1, t1);
        bar(); asm volatile("s_waitcnt lgkmcnt(0)" ::: "memory");
        mma(1, 0, a1); bar();
        // ph2: Q(1,1)
        ldB(0, 1); stage(0, 0, 0, t2);
        bar(); asm volatile("s_waitcnt lgkmcnt(0)" ::: "memory");
        mma(1, 1, a1); bar();
        // ph3: Q(0,1); counted vmcnt before slot-1 reads
        stage(0, 0, 1, t2);
        bar();
        mma(0, 1, a0);
        asm volatile("s_waitcnt vmcnt(4)" ::: "memory");
        bar();
        // ph4: Q(0,0) of tile 2it+1 (slot 1); 12 ds_reads -> pre-drain to 8
        ldA(1, 0, a0); ldB(1, 0); stage(0, 1, 0, t2);
        asm volatile("s_waitcnt lgkmcnt(8)" ::: "memory");
        bar(); asm volatile("s_waitcnt lgkmcnt(0)" ::: "memory");
        mma(0, 0, a0); bar();
        // ph5: Q(1,0)
        ldA(1, 1, a1); stage(0, 1, 1, t2);
        bar(); asm volatile("s_waitcnt lgkmcnt(0)" ::: "memory");
        mma(1, 0, a1); bar();
        // ph6: Q(1,1)
        ldB(1, 1); stage(1, 0, 0, t3);
        bar(); asm volatile("s_waitcnt lgkmcnt(0)" ::: "memory");
        mma(1, 1, a1); bar();
        // ph7: Q(0,1); counted vmcnt before next-iter slot-0 reads
        stage(1, 0, 1, t3);
        bar();
        mma(0, 1, a0);
        asm volatile("s_waitcnt vmcnt(4)" ::: "memory");
        bar();
    }

    // drain remaining async LDS-writes before epilogue / wave exit
    asm volatile("s_waitcnt vmcnt(0)" ::: "memory");

    // epilogue: out = acc * (s_row * scale_col) + bias  (exact int32 -> fp32)
    float srv[8][4];
    const float* smr = sm + tm * 256 + wr * 128 + kg * 4;
    #pragma unroll
    for (int mi = 0; mi < 8; ++mi)
        #pragma unroll
        for (int j = 0; j < 4; ++j)
            srv[mi][j] = smr[mi * 16 + j];

    #pragma unroll
    for (int ni = 0; ni < 4; ++ni) {
        const int col = tn * 256 + wc * 64 + ni * 16 + fr;
        const float s  = scale[col];
        const float bv = bias[col];
        #pragma unroll
        for (int mi = 0; mi < 8; ++mi) {
            const int row0 = tm * 256 + wr * 128 + mi * 16 + kg * 4;
            #pragma unroll
            for (int j = 0; j < 4; ++j)
                __builtin_nontemporal_store((float)acc[mi][ni][j] * (srv[mi][j] * s) + bv,
                                            out + (size_t)(row0 + j) * N_TOT + col);
        }
    }
}

// ---------------- fallback: round-1 fused fp16 kernel (known good, no ws) ----------------
constexpr int LDSS = 40;

__global__ __launch_bounds__(256, 2)
void int4lin_fused_kernel(const float* __restrict__ X,
                          const int*   __restrict__ Q,
                          const float* __restrict__ scale,
                          const float* __restrict__ bias,
                          float*       __restrict__ out)
{
    __shared__ _Float16 As[2][128][LDSS];
    __shared__ _Float16 Bs[2][128][LDSS];

    const int tid  = threadIdx.x;
    const int lane = tid & 63;
    const int bx   = blockIdx.x;
    const int by   = blockIdx.y;
    const int wave = tid >> 6;
    const int wm   = (wave >> 1) * 64;
    const int wn   = (wave & 1) * 64;
    const int fr   = lane & 15;
    const int kg   = lane >> 4;

    const int srow  = tid >> 1;
    const int shalf = tid & 1;

    const float* aptr = X + (size_t)(by * 128 + srow) * K_TOT + shalf * 16;
    const int*   bptr = Q + (size_t)(bx * 128 + srow) * PACKEDC + shalf * 8;

    floatx4 acc[4][4];
    #pragma unroll
    for (int i = 0; i < 4; ++i)
        #pragma unroll
        for (int j = 0; j < 4; ++j)
            acc[i][j] = (floatx4)0.0f;

    fvec4 araw[4];
    ivec4 braw[2];

    auto gload = [&](int kt) {
        const fvec4* ap = (const fvec4*)(aptr + (size_t)kt * 32);
        #pragma unroll
        for (int i = 0; i < 4; ++i) araw[i] = ap[i];
        const ivec4* bp = (const ivec4*)(bptr + kt * 16);
        #pragma unroll
        for (int i = 0; i < 2; ++i) braw[i] = bp[i];
    };

    auto cvt_write = [&](int buf) {
        #pragma unroll
        for (int v = 0; v < 2; ++v) {
            half8 h;
            #pragma unroll
            for (int e = 0; e < 8; ++e)
                h[e] = (_Float16)araw[v * 2 + (e >> 2)][e & 3];
            *(half8*)&As[buf][srow][shalf * 16 + v * 8] = h;
        }
        #pragma unroll
        for (int v = 0; v < 2; ++v) {
            half8 h;
            #pragma unroll
            for (int e = 0; e < 4; ++e) {
                const int b = braw[v][e];
                h[2 * e]     = (_Float16)((b & 15) - 8);
                h[2 * e + 1] = (_Float16)((b >> 4) - 8);
            }
            *(half8*)&Bs[buf][srow][shalf * 16 + v * 8] = h;
        }
    };

    gload(0);
    cvt_write(0);
    __syncthreads();

    int cur = 0;
    #pragma unroll 1
    for (int kt = 0; kt < K_TOT / 32; ++kt) {
        if (kt + 1 < K_TOT / 32) gload(kt + 1);

        half8 af[4], bf[4];
        #pragma unroll
        for (int mi = 0; mi < 4; ++mi)
            af[mi] = *(const half8*)&As[cur][wm + mi * 16 + fr][kg * 8];
        #pragma unroll
        for (int ni = 0; ni < 4; ++ni)
            bf[ni] = *(const half8*)&Bs[cur][wn + ni * 16 + fr][kg * 8];

        #pragma unroll
        for (int mi = 0; mi < 4; ++mi)
            #pragma unroll
            for (int ni = 0; ni < 4; ++ni)
                acc[mi][ni] = __builtin_amdgcn_mfma_f32_16x16x32_f16(
                    af[mi], bf[ni], acc[mi][ni], 0, 0, 0);

        if (kt + 1 < K_TOT / 32) cvt_write(cur ^ 1);
        __syncthreads();
        cur ^= 1;
    }

    #pragma unroll
    for (int ni = 0; ni < 4; ++ni) {
        const int col = bx * 128 + wn + ni * 16 + fr;
        const float s  = scale[col];
        const float bv = bias[col];
        #pragma unroll
        for (int mi = 0; mi < 4; ++mi) {
            const int row0 = by * 128 + wm + mi * 16 + kg * 4;
            #pragma unroll
            for (int j = 0; j < 4; ++j)
                out[(size_t)(row0 + j) * N_TOT + col] = acc[mi][ni][j] * s + bv;
        }
    }
}

extern "C" void kernel_launch(void* const* d_in, const int* in_sizes, int n_in,
                              void* d_out, int out_size, void* d_ws, size_t ws_size,
                              hipStream_t stream) {
    const float* x     = (const float*)d_in[0];
    const int*   q     = (const int*)d_in[1];
    const float* scale = (const float*)d_in[2];
    const float* bias  = (const float*)d_in[3];
    float*       out   = (float*)d_out;

    if (ws_size >= XQ_BYTES + SM_BYTES + WQ_BYTES) {
        signed char* xq = (signed char*)d_ws;
        float*       sm = (float*)((char*)d_ws + XQ_BYTES);
        signed char* wq = (signed char*)((char*)d_ws + XQ_BYTES + SM_BYTES);
        quant_x_kernel<<<M_TOT, 256, 0, stream>>>(x, xq, sm);
        quant_q_kernel<<<2048, 256, 0, stream>>>(q, wq, N_TOT * PACKEDC / 8);
        gemm8p_i8_kernel<<<(M_TOT / 256) * (N_TOT / 256), 512, 0, stream>>>(
            xq, wq, sm, scale, bias, out);
    } else {
        dim3 grid(N_TOT / 128, M_TOT / 128);
        int4lin_fused_kernel<<<grid, dim3(256), 0, stream>>>(x, q, scale, bias, out);
    }
}